// Round 7
// baseline (140.338 us; speedup 1.0000x reference)
//
#include <hip/hip_runtime.h>

#define Nn 2048
#define FIN 512
#define FO 64
#define SHIFT 20.0f
#define NJT 2
#define JSEG 1024
#define CHK 256

typedef __attribute__((ext_vector_type(8))) short bf16x8;
typedef __attribute__((ext_vector_type(4))) float f32x4;

__device__ __forceinline__ unsigned rne_bf16(float x) {   // low 16 bits = bf16(x), RNE
    unsigned u = __float_as_uint(x);
    return (u + 0x7FFFu + ((u >> 16) & 1u)) >> 16;
}
__device__ __forceinline__ float bf16_f32(unsigned s) { return __uint_as_float(s << 16); }

// ---------------- K1: h = x @ W (proven, deterministic) ----------------
__global__ __launch_bounds__(256) void gat_xw(const float* __restrict__ x,
                                              const float* __restrict__ W,
                                              float* __restrict__ h) {
    __shared__ float part[2][2][FO];
    const int wave = threadIdx.x >> 6;
    const int lane = threadIdx.x & 63;
    const int rs = wave >> 1;
    const int kh = wave & 1;
    int row = blockIdx.x * 2 + rs;
    row = __builtin_amdgcn_readfirstlane(row);
    const float* xr = x + (size_t)row * FIN + kh * (FIN / 2);
    const float* Wp = W + (size_t)kh * (FIN / 2) * FO;
    float acc = 0.f;
#pragma unroll 2
    for (int k = 0; k < FIN / 2; k += 8) {
        float4 xa = *(const float4*)(xr + k);
        float4 xb = *(const float4*)(xr + k + 4);
        acc = fmaf(xa.x, Wp[(k + 0) * FO + lane], acc);
        acc = fmaf(xa.y, Wp[(k + 1) * FO + lane], acc);
        acc = fmaf(xa.z, Wp[(k + 2) * FO + lane], acc);
        acc = fmaf(xa.w, Wp[(k + 3) * FO + lane], acc);
        acc = fmaf(xb.x, Wp[(k + 4) * FO + lane], acc);
        acc = fmaf(xb.y, Wp[(k + 5) * FO + lane], acc);
        acc = fmaf(xb.z, Wp[(k + 6) * FO + lane], acc);
        acc = fmaf(xb.w, Wp[(k + 7) * FO + lane], acc);
    }
    part[rs][kh][lane] = acc;
    __syncthreads();
    if (threadIdx.x < 128) {
        const int r2 = threadIdx.x >> 6;
        const int l2 = threadIdx.x & 63;
        h[((size_t)blockIdx.x * 2 + r2) * FO + l2] = part[r2][0][l2] + part[r2][1][l2];
    }
}

// ---------------- K1b: hbT_hi/lo[f][j] = bf16 split of h[j][f] ----------------
__global__ __launch_bounds__(256) void gat_tr(const float* __restrict__ h,
                                              unsigned short* __restrict__ hbT_hi,
                                              unsigned short* __restrict__ hbT_lo) {
    __shared__ float t_s[64 * 68];
    const int tid = threadIdx.x;
    const int j0 = blockIdx.x * 64;       // grid 32
    for (int g4 = tid; g4 < 1024; g4 += 256) {
        float4 v = *(const float4*)(h + (size_t)j0 * FO + (size_t)g4 * 4);
        *(float4*)&t_s[(g4 >> 4) * 68 + (g4 & 15) * 4] = v;
    }
    __syncthreads();
    const int f = tid >> 2, q = tid & 3;
    unsigned* dh = (unsigned*)&hbT_hi[(size_t)f * Nn + j0 + q * 16];
    unsigned* dl = (unsigned*)&hbT_lo[(size_t)f * Nn + j0 + q * 16];
#pragma unroll
    for (int u = 0; u < 8; u++) {
        float x0 = t_s[(q * 16 + 2 * u) * 68 + f];
        float x1 = t_s[(q * 16 + 2 * u + 1) * 68 + f];
        unsigned h0 = rne_bf16(x0), h1 = rne_bf16(x1);
        dh[u] = h0 | (h1 << 16);
        float r0 = x0 - bf16_f32(h0), r1 = x1 - bf16_f32(h1);
        dl[u] = rne_bf16(r0) | (rne_bf16(r1) << 16);
    }
}

// ---------------- K2: deterministic fused attention ----------------
// Grid 256 = 128 i-tiles (16 rows) x 2 j-segments (1024). Block 256 thr = 4 waves.
// e-phase f32: thread (ig=tid>>7 wave-uniform, jg=tid&127) tile 8i x 2j; hj from
// XOR-swizzled LDS (b128, conflict-free); hi & a wave-uniform global loads (off
// the LDS pipe). PV: P and h split hi+lo bf16 -> 3 MFMA/k-step (error ~2^-18).
// No atomics: opart/lpart writes are block-exclusive -> bit-reproducible.
__global__ __launch_bounds__(256) void gat_attn7(const float* __restrict__ h,
                                                 const int* __restrict__ adj,
                                                 const float* __restrict__ a,
                                                 const unsigned short* __restrict__ hbT_hi,
                                                 const unsigned short* __restrict__ hbT_lo,
                                                 float* __restrict__ opart,
                                                 float* __restrict__ lpart) {
    __shared__ float hj_s[CHK * 64];             // 64 KB, f-quads XOR-swizzled by (j&7)
    __shared__ unsigned short Ph_s[16 * 264];    // 8.4 KB, 528B rows (16B-aligned)
    __shared__ unsigned short Pl_s[16 * 264];

    const int tid = threadIdx.x;
    const int it = blockIdx.x >> 1;
    const int jt = blockIdx.x & 1;
    const int ib = it * 16;
    const int jb = jt * JSEG;
    const int ig = __builtin_amdgcn_readfirstlane(tid >> 7);  // wave-uniform i-group
    const int jg = tid & 127;
    const int lane = tid & 63;
    const int w = tid >> 6;
    const int m = lane & 15;
    const int g = lane >> 4;

    float ls[8] = {0.f, 0.f, 0.f, 0.f, 0.f, 0.f, 0.f, 0.f};
    f32x4 acc = {0.f, 0.f, 0.f, 0.f};

    for (int jc = 0; jc < JSEG; jc += CHK) {
        __syncthreads();    // prev chunk: MFMA done with Ph/Pl, e done with hj
        const float* hsrc = h + (size_t)(jb + jc) * FO;
        for (int g4 = tid; g4 < 4096; g4 += 256) {
            const int j = g4 >> 4, c = g4 & 15;
            *(float4*)&hj_s[j * 64 + ((c ^ (j & 7)) << 2)] =
                *(const float4*)(hsrc + (size_t)g4 * 4);
        }
        __syncthreads();

        const int j0 = jg * 2, j1 = j0 + 1;
        int2 am[8];
        const int* adjp = adj + (size_t)(ib + ig * 8) * Nn + (jb + jc + j0);
#pragma unroll
        for (int ii = 0; ii < 8; ii++) am[ii] = *(const int2*)(adjp + (size_t)ii * Nn);

        float e[8][2];
#pragma unroll
        for (int ii = 0; ii < 8; ii++) e[ii][0] = e[ii][1] = 0.f;

#pragma unroll 2
        for (int fq = 0; fq < 16; fq++) {
            const int f = fq * 4;
            const float4 av = *(const float4*)(a + f);                       // uniform
            const float4 hj0 = *(const float4*)&hj_s[j0 * 64 + ((fq ^ (j0 & 7)) << 2)];
            const float4 hj1 = *(const float4*)&hj_s[j1 * 64 + ((fq ^ (j1 & 7)) << 2)];
#pragma unroll
            for (int ii = 0; ii < 8; ii++) {
                const float4 hi = *(const float4*)(h + (size_t)(ib + ig * 8 + ii) * FO + f);
                e[ii][0] = fmaf(fabsf(hi.x - hj0.x), av.x, e[ii][0]);
                e[ii][0] = fmaf(fabsf(hi.y - hj0.y), av.y, e[ii][0]);
                e[ii][0] = fmaf(fabsf(hi.z - hj0.z), av.z, e[ii][0]);
                e[ii][0] = fmaf(fabsf(hi.w - hj0.w), av.w, e[ii][0]);
                e[ii][1] = fmaf(fabsf(hi.x - hj1.x), av.x, e[ii][1]);
                e[ii][1] = fmaf(fabsf(hi.y - hj1.y), av.y, e[ii][1]);
                e[ii][1] = fmaf(fabsf(hi.z - hj1.z), av.z, e[ii][1]);
                e[ii][1] = fmaf(fabsf(hi.w - hj1.w), av.w, e[ii][1]);
            }
        }

        // p = adj ? exp(relu(e)-SHIFT) : 0  (shift-invariant, exact); split hi/lo bf16
#pragma unroll
        for (int ii = 0; ii < 8; ii++) {
            const float p0 = (am[ii].x > 0) ? __expf(fmaxf(e[ii][0], 0.f) - SHIFT) : 0.f;
            const float p1 = (am[ii].y > 0) ? __expf(fmaxf(e[ii][1], 0.f) - SHIFT) : 0.f;
            ls[ii] += p0 + p1;
            const unsigned h0 = rne_bf16(p0), h1 = rne_bf16(p1);
            const float r0 = p0 - bf16_f32(h0), r1 = p1 - bf16_f32(h1);
            ((unsigned*)Ph_s)[(ig * 8 + ii) * 132 + jg] = h0 | (h1 << 16);
            ((unsigned*)Pl_s)[(ig * 8 + ii) * 132 + jg] =
                rne_bf16(r0) | (rne_bf16(r1) << 16);
        }
        __syncthreads();    // P complete

        // MFMA: wave w owns f-tile w (16 f), C-resident across chunks
        const size_t bbase = (size_t)(w * 16 + m) * Nn + (jb + jc);
#pragma unroll
        for (int ks = 0; ks < 8; ks++) {
            const bf16x8 af = *(const bf16x8*)&Ph_s[m * 264 + ks * 32 + g * 8];
            const bf16x8 al = *(const bf16x8*)&Pl_s[m * 264 + ks * 32 + g * 8];
            const bf16x8 bh = *(const bf16x8*)&hbT_hi[bbase + ks * 32 + g * 8];
            const bf16x8 bl = *(const bf16x8*)&hbT_lo[bbase + ks * 32 + g * 8];
            acc = __builtin_amdgcn_mfma_f32_16x16x32_bf16(af, bh, acc, 0, 0, 0);
            acc = __builtin_amdgcn_mfma_f32_16x16x32_bf16(af, bl, acc, 0, 0, 0);
            acc = __builtin_amdgcn_mfma_f32_16x16x32_bf16(al, bh, acc, 0, 0, 0);
        }
    }

    // ---- epilogue: l-reduction via LDS (reuse hj_s), exclusive partial writes ----
    __syncthreads();
    float* red = hj_s;
#pragma unroll
    for (int ii = 0; ii < 8; ii++) red[(ig * 8 + ii) * 132 + jg] = ls[ii];
    __syncthreads();
    if (tid < 16) {
        float l = 0.f;
        for (int c2 = 0; c2 < 128; c2++) l += red[tid * 132 + c2];
        lpart[(size_t)jt * Nn + ib + tid] = l;
    }
    // C/D layout: col = lane&15 = f-within-tile, row = g*4+r = i-within-tile
#pragma unroll
    for (int r = 0; r < 4; r++)
        opart[((size_t)jt * Nn + ib + g * 4 + r) * FO + w * 16 + m] = acc[r];
}

// ---------------- K3: fixed-order merge + normalize + relu ----------------
__global__ __launch_bounds__(256) void gat_merge(const float* __restrict__ opart,
                                                 const float* __restrict__ lpart,
                                                 float* __restrict__ out) {
    const int t = blockIdx.x * 256 + threadIdx.x;   // grid 512 -> 131072
    const int i = t >> 6;
    const float o = opart[t] + opart[(size_t)Nn * FO + t];
    const float l = lpart[i] + lpart[Nn + i];
    out[t] = fmaxf(o / l, 0.f);
}

extern "C" void kernel_launch(void* const* d_in, const int* in_sizes, int n_in,
                              void* d_out, int out_size, void* d_ws, size_t ws_size,
                              hipStream_t stream) {
    const float* x   = (const float*)d_in[0];
    const int*   adj = (const int*)d_in[1];
    const float* W   = (const float*)d_in[2];
    const float* a   = (const float*)d_in[3];
    float* out = (float*)d_out;

    float* h     = (float*)d_ws;                       // 131072 f32
    float* opart = h + (size_t)Nn * FO;                // 2*131072 f32
    float* lpart = opart + (size_t)NJT * Nn * FO;      // 2*2048 f32
    unsigned short* hbT_hi = (unsigned short*)(lpart + (size_t)NJT * Nn);  // 256 KB
    unsigned short* hbT_lo = hbT_hi + (size_t)FO * Nn;                     // 256 KB
    // total ws = 2.02 MB (< round-2-proven 2.73 MB envelope)

    gat_xw<<<dim3(1024), dim3(256), 0, stream>>>(x, W, h);
    gat_tr<<<dim3(32), dim3(256), 0, stream>>>(h, hbT_hi, hbT_lo);
    gat_attn7<<<dim3(256), dim3(256), 0, stream>>>(h, adj, a, hbT_hi, hbT_lo, opart, lpart);
    gat_merge<<<dim3(512), dim3(256), 0, stream>>>(opart, lpart, out);
}